// Round 7
// baseline (4417.390 us; speedup 1.0000x reference)
//
#include <hip/hip_runtime.h>
#include <hip/hip_bf16.h>
#include <cstdint>
#include <cstddef>

#define D 256
#define RNUM 8
#define LAYERS 3
#define SEGS 9            // root + 8 relations
#define KSTEPS 8          // 256 / 32
#define BM 64             // dst rows per block
#define NWAVE 8           // waves per block
#define AST 264           // A LDS row stride (fp16 elems)
#define SMASK 0x03FFFFFF  // low 26 bits: src node id

typedef _Float16 f16x8 __attribute__((ext_vector_type(8)));  // 8 fp16 (4 VGPRs)
typedef float f32x4  __attribute__((ext_vector_type(4)));    // MFMA accumulator

__device__ __forceinline__ unsigned short f2h(float f) {
    union { _Float16 h; unsigned short u; } x;
    x.h = (_Float16)f;                 // RNE
    return x.u;
}
__device__ __forceinline__ float h2f(unsigned short u) {
    union { _Float16 h; unsigned short u; } x;
    x.u = u;
    return (float)x.h;
}

// Raw workgroup barrier WITHOUT vmcnt drain: only LDS ops must be visible at
// the barrier; global-load prefetches (B frags, edge lists) stay in flight.
__device__ __forceinline__ void wave_barrier() {
    asm volatile("s_waitcnt lgkmcnt(0)" ::: "memory");
    __builtin_amdgcn_s_barrier();
    asm volatile("" ::: "memory");
    __builtin_amdgcn_sched_barrier(0);
}

// ---------------------------------------------------------------------------
// ws layout (bytes):
//   [0]     int flag
//   [256]   int pp[N*8+1]      counts -> exclusive scan (CSR over (rel,dst))
//   [..]    int cur[N*8], int bsum[512], int epk[E]   (packed lr|src)
//   [a1]    float h1[N*D]                                  51.2 MB
//   [a2]    ushort wblk[3*9*8*2*256*32]                    7.1 MB
// ---------------------------------------------------------------------------

__global__ void zero_kernel(int* __restrict__ p, int n) {
    int i = blockIdx.x * blockDim.x + threadIdx.x;
    if (i < n) p[i] = 0;
}

__global__ void detect_kernel(const int* __restrict__ ei32, int* __restrict__ flag) {
    __shared__ int allzero;
    if (threadIdx.x == 0) allzero = 1;
    __syncthreads();
    if (ei32[2 * threadIdx.x + 1] != 0) allzero = 0;  // benign race: all write 0
    __syncthreads();
    if (threadIdx.x == 0) flag[0] = allzero;
}

__device__ __forceinline__ void load_edge(const void* ei, const void* et, int flg,
                                          int e, int E, int N,
                                          int& s, int& d, int& r) {
    if (flg) {
        const long long* a = (const long long*)ei;
        const long long* b = (const long long*)et;
        s = (int)a[e]; d = (int)a[E + e]; r = (int)b[e];
    } else {
        const int* a = (const int*)ei;
        const int* b = (const int*)et;
        s = a[e]; d = a[E + e]; r = b[e];
    }
    if ((unsigned)s >= (unsigned)N) s = 0;
    if ((unsigned)d >= (unsigned)N) d = 0;
    if ((unsigned)r >= (unsigned)RNUM) r = 0;
}

__global__ void count_kernel(const void* __restrict__ ei, const void* __restrict__ et,
                             const int* __restrict__ flag, int* __restrict__ pp,
                             int E, int N) {
    int e = blockIdx.x * blockDim.x + threadIdx.x;
    if (e >= E) return;
    int s, d, r;
    load_edge(ei, et, flag[0], e, E, N, s, d, r);
    atomicAdd(&pp[r * N + d], 1);      // key = rel*N + dst
}

__global__ void scan_blocks_kernel(int* __restrict__ pp, int* __restrict__ bsum, int n) {
    __shared__ int sb[1024];
    const int t = threadIdx.x;
    const int i = blockIdx.x * 1024 + t;
    const int v = (i < n) ? pp[i] : 0;
    sb[t] = v;
    __syncthreads();
    for (int off = 1; off < 1024; off <<= 1) {
        int x = 0;
        if (t >= off) x = sb[t - off];
        __syncthreads();
        if (t >= off) sb[t] += x;
        __syncthreads();
    }
    if (i < n) pp[i] = sb[t] - v;
    if (t == 1023) bsum[blockIdx.x] = sb[t];
}

__global__ void scan_sums_kernel(int* __restrict__ bsum, int nb) {
    __shared__ int sb[512];
    const int t = threadIdx.x;
    const int v = (t < nb) ? bsum[t] : 0;
    sb[t] = v;
    __syncthreads();
    for (int off = 1; off < 512; off <<= 1) {
        int x = 0;
        if (t >= off) x = sb[t - off];
        __syncthreads();
        if (t >= off) sb[t] += x;
        __syncthreads();
    }
    if (t < nb) bsum[t] = sb[t] - v;
}

__global__ void scan_add_kernel(int* __restrict__ pp, const int* __restrict__ bsum,
                                int n, int E) {
    const int i = blockIdx.x * 1024 + threadIdx.x;
    if (i < n) pp[i] += bsum[blockIdx.x];
    if (i == 0) pp[n] = E;
}

__global__ void fill_kernel(const void* __restrict__ ei, const void* __restrict__ et,
                            const int* __restrict__ flag, const int* __restrict__ pp,
                            int* __restrict__ cur, int* __restrict__ epk,
                            int E, int N) {
    int e = blockIdx.x * blockDim.x + threadIdx.x;
    if (e >= E) return;
    int s, d, r;
    load_edge(ei, et, flag[0], e, E, N, s, d, r);
    const int key = r * N + d;
    const int pos = atomicAdd(&cur[key], 1);
    const int slot = pp[key] + pos;
    if ((unsigned)slot < (unsigned)E)
        epk[slot] = ((d & (BM - 1)) << 26) | (s & SMASK);   // block-local row | src
}

// ---------------------------------------------------------------------------
// W -> blocked fp16 hi/lo: wblk[l][seg][ks][hi/lo][col][kk] = B[ks*32+kk][col]
// (A side is single-fp16; B keeps the fp16 hi/lo split -> B rel err ~2^-22.)
// ---------------------------------------------------------------------------
__global__ void wconvert_kernel(const float* __restrict__ weights,
                                const float* __restrict__ roots,
                                unsigned short* __restrict__ wblk) {
    const int total = LAYERS * SEGS * KSTEPS * 256 * 32;
    int idx = blockIdx.x * blockDim.x + threadIdx.x;
    if (idx >= total) return;
    const int kk  = idx & 31;
    const int col = (idx >> 5) & 255;
    const int ks  = (idx >> 13) & 7;
    const int sl  = idx >> 16;            // l*9 + seg
    const int seg = sl % SEGS, l = sl / SEGS;
    const int krow = ks * 32 + kk;
    float v;
    if (seg == 0)
        v = roots[((size_t)l * 256 + krow) * 256 + col];
    else
        v = weights[(((size_t)l * RNUM + (seg - 1)) * 256 + krow) * 256 + col];
    const unsigned short hi = f2h(v);
    const unsigned short lo = f2h(v - h2f(hi));
    const size_t base = ((size_t)sl * KSTEPS + ks) * 16384;
    wblk[base + (size_t)col * 32 + kk] = hi;
    wblk[base + 8192 + (size_t)col * 32 + kk] = lo;
}

// ---------------------------------------------------------------------------
// Fused RGCN layer, round 7: fp16 A (single) + fp16 hi/lo B -> 2 products/ks.
//   - R6 structure kept (one A array, 33.8 KB LDS -> 4 blocks/CU, 16 MFMA/ks,
//     half the LDS reads) but in fp16: A rel err 2^-12 (8x finer than bf16),
//     fixing R6's 4.49e-2 absmax failure (predicted ~1e-2 < 2e-2).
//   - __launch_bounds__(512, 8) pins VGPR <= 64 (8 waves/SIMD gate).
// ---------------------------------------------------------------------------
template <int ACT>  // 0 = relu, 1 = sigmoid
__global__ __launch_bounds__(512, 8)
void layer_kernel(const float* __restrict__ hin,            // [N, D] fp32
                  const unsigned short* __restrict__ wl,    // this layer's wblk
                  const float* __restrict__ bias,           // [D]
                  const int* __restrict__ pp,               // [N*8+1], key=r*N+d
                  const int* __restrict__ epk,              // [E] packed lr|src
                  float* __restrict__ hout,                 // [N, D]
                  int N) {
    __shared__ unsigned short Ahi[BM * AST];   // 33,792 B

    const int tid = threadIdx.x;
    const int wv = tid >> 6;          // wave 0..7 -> cols [wv*32, wv*32+32)
    const int lane = tid & 63;
    const int lm = lane & 15;         // MFMA row/col lane index
    const int lq = lane >> 4;         // MFMA k-quad
    const int rb = blockIdx.x * BM;
    const int cbase = wv * 32 + lm;

    f32x4 acc[4][2];                  // [row-tile][col-tile]
#pragma unroll
    for (int i = 0; i < 4; ++i)
#pragma unroll
        for (int j = 0; j < 2; ++j) acc[i][j] = (f32x4)0.f;

    // ---- hoist all segment range boundaries: lane l<16 -> (rel=l>>1, fence=l&1)
    int bnd = 0;
    if (lane < 16) {
        const int r = lane >> 1;
        int row = rb + wv * 8 + ((lane & 1) << 3);
        if (row > N) row = N;                   // tail clamp -> empty ranges
        bnd = pp[r * N + row];
    }

    auto flushrow = [&](int row, const float4& s) {
        ushort4 h4;
        h4.x = f2h(s.x); h4.y = f2h(s.y);
        h4.z = f2h(s.z); h4.w = f2h(s.w);
        *reinterpret_cast<ushort4*>(&Ahi[row * AST + lane * 4]) = h4;
    };

    // ---- stage seg 0 (root): dense copy of block rows
    for (int m = wv; m < BM; m += NWAVE) {
        int r = rb + m;
        if (r >= N) r = N - 1;                 // tail clamp; store is masked later
        const float4 v = *reinterpret_cast<const float4*>(hin + (size_t)r * D + lane * 4);
        ushort4 h4;
        h4.x = f2h(v.x); h4.y = f2h(v.y);
        h4.z = f2h(v.z); h4.w = f2h(v.w);
        *reinterpret_cast<ushort4*>(&Ahi[m * AST + lane * 4]) = h4;
    }

    // ---- prefetch edge list for segment 1
    int nbeg = __builtin_amdgcn_readlane(bnd, 0);
    int ncnt = __builtin_amdgcn_readlane(bnd, 1) - nbeg;
    int ep = 0;
    { const int c = ncnt < 64 ? ncnt : 64; if (lane < c) ep = epk[nbeg + lane]; }

    wave_barrier();    // seg-0 tile visible

    for (int seg = 0; seg < SEGS; ++seg) {
        // ============ MFMA phase on staged A tile ============
        const unsigned short* wseg = wl + (size_t)seg * KSTEPS * 16384;
        for (int ks = 0; ks < KSTEPS; ++ks) {
            const unsigned short* wks = wseg + (size_t)ks * 16384;
            // B fragments from global (L2): lane holds B[k = lq*8+j][col]
            f16x8 bh[2], bl[2];
#pragma unroll
            for (int ct = 0; ct < 2; ++ct) {
                const int c = cbase + ct * 16;
                bh[ct] = *reinterpret_cast<const f16x8*>(wks + (size_t)c * 32 + lq * 8);
                bl[ct] = *reinterpret_cast<const f16x8*>(wks + 8192 + (size_t)c * 32 + lq * 8);
            }
            // A fragments: lane holds A[m = rt*16+lm][k = lq*8 + j]
            f16x8 ah[4];
#pragma unroll
            for (int rt = 0; rt < 4; ++rt) {
                const int off = (rt * 16 + lm) * AST + ks * 32 + lq * 8;
                ah[rt] = *reinterpret_cast<const f16x8*>(&Ahi[off]);
            }
#pragma unroll
            for (int rt = 0; rt < 4; ++rt)
#pragma unroll
                for (int ct = 0; ct < 2; ++ct) {
                    acc[rt][ct] = __builtin_amdgcn_mfma_f32_16x16x32_f16(
                        ah[rt], bl[ct], acc[rt][ct], 0, 0, 0);
                    acc[rt][ct] = __builtin_amdgcn_mfma_f32_16x16x32_f16(
                        ah[rt], bh[ct], acc[rt][ct], 0, 0, 0);
                }
        }

        // ============ stage next segment ============
        if (seg + 1 < SEGS) {
            wave_barrier();            // all waves done reading the A tile

            // zero this wave's 8 rows (covers edge-less rows; flushes overwrite)
#pragma unroll
            for (int m = 0; m < 8; ++m) {
                const int row = wv * 8 + m;
                *reinterpret_cast<ushort4*>(&Ahi[row * AST + lane * 4]) =
                    make_ushort4(0, 0, 0, 0);
            }

            // gather: run-accumulate the wave's contiguous edge range
            {
                const int beg = nbeg, cnt = ncnt;
                int e0 = ep;
                int cur = -1;
                float4 sum = make_float4(0.f, 0.f, 0.f, 0.f);
                int processed = 0;
                while (processed < cnt) {
                    int avail = cnt - processed;
                    if (avail > 64) avail = 64;
                    int inner = 0;
                    while (inner < avail) {
                        const int take = (avail - inner) < 8 ? (avail - inner) : 8;
                        int pk[8]; float4 u[8];
#pragma unroll
                        for (int i = 0; i < 8; ++i) {
                            if (i < take) {
                                pk[i] = __builtin_amdgcn_readlane(e0, inner + i);
                                const int s = pk[i] & SMASK;
                                u[i] = *reinterpret_cast<const float4*>(
                                    hin + (size_t)s * D + lane * 4);
                            }
                        }
#pragma unroll
                        for (int i = 0; i < 8; ++i) {
                            if (i < take) {
                                const int lr = (int)(((unsigned)pk[i]) >> 26);
                                if (lr != cur) {
                                    if (cur >= 0) flushrow(cur, sum);
                                    sum = make_float4(0.f, 0.f, 0.f, 0.f);
                                    cur = lr;
                                }
                                sum.x += u[i].x; sum.y += u[i].y;
                                sum.z += u[i].z; sum.w += u[i].w;
                            }
                        }
                        inner += take;
                    }
                    processed += avail;
                    if (processed < cnt) {
                        int c = cnt - processed; if (c > 64) c = 64;
                        e0 = 0;
                        if (lane < c) e0 = epk[beg + processed + lane];
                    }
                }
                if (cur >= 0) flushrow(cur, sum);
            }

            // prefetch edge list for segment seg+2 (hides under next MFMA phase)
            if (seg + 2 < SEGS) {
                nbeg = __builtin_amdgcn_readlane(bnd, (seg + 1) * 2);
                ncnt = __builtin_amdgcn_readlane(bnd, (seg + 1) * 2 + 1) - nbeg;
                ep = 0;
                const int c = ncnt < 64 ? ncnt : 64;
                if (lane < c) ep = epk[nbeg + lane];
            }

            wave_barrier();            // staged A tile visible
        }
    }

    // ---- epilogue: C/D layout col=lane&15, row=(lane>>4)*4+reg
#pragma unroll
    for (int ct = 0; ct < 2; ++ct) {
        const int col = wv * 32 + ct * 16 + lm;
        const float bb = bias[col];
#pragma unroll
        for (int rt = 0; rt < 4; ++rt) {
#pragma unroll
            for (int i = 0; i < 4; ++i) {
                const int row = rb + rt * 16 + lq * 4 + i;
                if (row < N) {
                    float z = acc[rt][ct][i] + bb;
                    z = (ACT == 0) ? fmaxf(z, 0.f) : 1.f / (1.f + __expf(-z));
                    hout[(size_t)row * D + col] = z;
                }
            }
        }
    }
}

// ---------------------------------------------------------------------------
extern "C" void kernel_launch(void* const* d_in, const int* in_sizes, int n_in,
                              void* d_out, int out_size, void* d_ws, size_t ws_size,
                              hipStream_t stream) {
    const float* x       = (const float*)d_in[0];
    const float* weights = (const float*)d_in[1];   // [L, R, D, D]
    const float* roots   = (const float*)d_in[2];   // [L, D, D]
    const float* biases  = (const float*)d_in[3];   // [L, D]
    const void*  ei      = d_in[4];                 // [2, E]
    const void*  et      = d_in[5];                 // [E]

    const int N = in_sizes[0] / D;    // 50000
    const int E = in_sizes[4] / 2;    // 300000
    const int NP = N * RNUM;          // 400000

    char* ws = (char*)d_ws;
    int* flag = (int*)ws;
    int* pp   = (int*)(ws + 256);     // NP+1
    int* cur  = pp + (NP + 1);        // NP
    int* bsum = cur + NP;             // 512
    int* epk  = bsum + 512;           // E (packed lr|src)
    size_t hoff = (256 + (size_t)(NP + 1 + NP + 512 + E) * 4 + 255) & ~(size_t)255;
    float* h1 = (float*)(ws + hoff);
    unsigned short* wblk = (unsigned short*)(ws + hoff + (size_t)N * D * sizeof(float));

    // --- W conversion to MFMA-blocked fp16 hi/lo (all 3 layers) ---
    const int wtotal = LAYERS * SEGS * KSTEPS * 256 * 32;
    wconvert_kernel<<<(wtotal + 255) / 256, 256, 0, stream>>>(weights, roots, wblk);

    // --- build (rel,dst)-sorted CSR ---
    detect_kernel<<<1, 256, 0, stream>>>((const int*)ei, flag);
    const int zn = 2 * NP + 513;
    zero_kernel<<<(zn + 255) / 256, 256, 0, stream>>>(pp, zn);
    const int eb = (E + 255) / 256;
    count_kernel<<<eb, 256, 0, stream>>>(ei, et, flag, pp, E, N);
    const int nb = (NP + 1023) / 1024;
    scan_blocks_kernel<<<nb, 1024, 0, stream>>>(pp, bsum, NP);
    scan_sums_kernel<<<1, 512, 0, stream>>>(bsum, nb);
    scan_add_kernel<<<nb, 1024, 0, stream>>>(pp, bsum, NP, E);
    fill_kernel<<<eb, 256, 0, stream>>>(ei, et, flag, pp, cur, epk, E, N);

    // --- 3 fused layers ---
    const int tiles = (N + BM - 1) / BM;   // 782
    const size_t wlayer = (size_t)SEGS * KSTEPS * 16384;
    const float* hin = x;
    for (int l = 0; l < LAYERS; ++l) {
        float* hout = (l == 1) ? h1 : (float*)d_out;   // l0->d_out, l1->h1, l2->d_out
        const unsigned short* wlp = wblk + (size_t)l * wlayer;
        const float* bl = biases + (size_t)l * D;
        if (l == LAYERS - 1)
            layer_kernel<1><<<tiles, 512, 0, stream>>>(hin, wlp, bl, pp, epk, hout, N);
        else
            layer_kernel<0><<<tiles, 512, 0, stream>>>(hin, wlp, bl, pp, epk, hout, N);
        hin = hout;
    }
}

// Round 8
// 732.060 us; speedup vs baseline: 6.0342x; 6.0342x over previous
//
#include <hip/hip_runtime.h>
#include <hip/hip_bf16.h>
#include <cstdint>
#include <cstddef>

#define D 256
#define RNUM 8
#define LAYERS 3
#define SEGS 9            // root + 8 relations
#define KSTEPS 8          // 256 / 32
#define BM 64             // dst rows per block
#define NWAVE 8           // waves per block
#define AST 264           // A LDS row stride (fp16 elems)
#define SMASK 0x03FFFFFF  // low 26 bits: src node id

typedef _Float16 f16x8 __attribute__((ext_vector_type(8)));  // 8 fp16 (4 VGPRs)
typedef float f32x4  __attribute__((ext_vector_type(4)));    // MFMA accumulator

__device__ __forceinline__ unsigned short f2h(float f) {
    union { _Float16 h; unsigned short u; } x;
    x.h = (_Float16)f;                 // RNE
    return x.u;
}
__device__ __forceinline__ float h2f(unsigned short u) {
    union { _Float16 h; unsigned short u; } x;
    x.u = u;
    return (float)x.h;
}

// Raw workgroup barrier WITHOUT vmcnt drain: only LDS ops must be visible at
// the barrier; global-load prefetches (B frags, edge lists) stay in flight.
__device__ __forceinline__ void wave_barrier() {
    asm volatile("s_waitcnt lgkmcnt(0)" ::: "memory");
    __builtin_amdgcn_s_barrier();
    asm volatile("" ::: "memory");
    __builtin_amdgcn_sched_barrier(0);
}

// ---------------------------------------------------------------------------
// ws layout (bytes):
//   [0]     int flag
//   [256]   int pp[N*8+1]      counts -> exclusive scan (CSR over (rel,dst))
//   [..]    int cur[N*8], int bsum[512], int epk[E]   (packed lr|src)
//   [a1]    float h1[N*D]                                  51.2 MB
//   [a2]    ushort wblk[3*9*8*2*256*32]                    7.1 MB
// ---------------------------------------------------------------------------

__global__ void zero_kernel(int* __restrict__ p, int n) {
    int i = blockIdx.x * blockDim.x + threadIdx.x;
    if (i < n) p[i] = 0;
}

__global__ void detect_kernel(const int* __restrict__ ei32, int* __restrict__ flag) {
    __shared__ int allzero;
    if (threadIdx.x == 0) allzero = 1;
    __syncthreads();
    if (ei32[2 * threadIdx.x + 1] != 0) allzero = 0;  // benign race: all write 0
    __syncthreads();
    if (threadIdx.x == 0) flag[0] = allzero;
}

__device__ __forceinline__ void load_edge(const void* ei, const void* et, int flg,
                                          int e, int E, int N,
                                          int& s, int& d, int& r) {
    if (flg) {
        const long long* a = (const long long*)ei;
        const long long* b = (const long long*)et;
        s = (int)a[e]; d = (int)a[E + e]; r = (int)b[e];
    } else {
        const int* a = (const int*)ei;
        const int* b = (const int*)et;
        s = a[e]; d = a[E + e]; r = b[e];
    }
    if ((unsigned)s >= (unsigned)N) s = 0;
    if ((unsigned)d >= (unsigned)N) d = 0;
    if ((unsigned)r >= (unsigned)RNUM) r = 0;
}

__global__ void count_kernel(const void* __restrict__ ei, const void* __restrict__ et,
                             const int* __restrict__ flag, int* __restrict__ pp,
                             int E, int N) {
    int e = blockIdx.x * blockDim.x + threadIdx.x;
    if (e >= E) return;
    int s, d, r;
    load_edge(ei, et, flag[0], e, E, N, s, d, r);
    atomicAdd(&pp[r * N + d], 1);      // key = rel*N + dst
}

__global__ void scan_blocks_kernel(int* __restrict__ pp, int* __restrict__ bsum, int n) {
    __shared__ int sb[1024];
    const int t = threadIdx.x;
    const int i = blockIdx.x * 1024 + t;
    const int v = (i < n) ? pp[i] : 0;
    sb[t] = v;
    __syncthreads();
    for (int off = 1; off < 1024; off <<= 1) {
        int x = 0;
        if (t >= off) x = sb[t - off];
        __syncthreads();
        if (t >= off) sb[t] += x;
        __syncthreads();
    }
    if (i < n) pp[i] = sb[t] - v;
    if (t == 1023) bsum[blockIdx.x] = sb[t];
}

__global__ void scan_sums_kernel(int* __restrict__ bsum, int nb) {
    __shared__ int sb[512];
    const int t = threadIdx.x;
    const int v = (t < nb) ? bsum[t] : 0;
    sb[t] = v;
    __syncthreads();
    for (int off = 1; off < 512; off <<= 1) {
        int x = 0;
        if (t >= off) x = sb[t - off];
        __syncthreads();
        if (t >= off) sb[t] += x;
        __syncthreads();
    }
    if (t < nb) bsum[t] = sb[t] - v;
}

__global__ void scan_add_kernel(int* __restrict__ pp, const int* __restrict__ bsum,
                                int n, int E) {
    const int i = blockIdx.x * 1024 + threadIdx.x;
    if (i < n) pp[i] += bsum[blockIdx.x];
    if (i == 0) pp[n] = E;
}

__global__ void fill_kernel(const void* __restrict__ ei, const void* __restrict__ et,
                            const int* __restrict__ flag, const int* __restrict__ pp,
                            int* __restrict__ cur, int* __restrict__ epk,
                            int E, int N) {
    int e = blockIdx.x * blockDim.x + threadIdx.x;
    if (e >= E) return;
    int s, d, r;
    load_edge(ei, et, flag[0], e, E, N, s, d, r);
    const int key = r * N + d;
    const int pos = atomicAdd(&cur[key], 1);
    const int slot = pp[key] + pos;
    if ((unsigned)slot < (unsigned)E)
        epk[slot] = ((d & (BM - 1)) << 26) | (s & SMASK);   // block-local row | src
}

// ---------------------------------------------------------------------------
// W -> blocked fp16 hi/lo: wblk[l][seg][ks][hi/lo][col][kk] = B[ks*32+kk][col]
// (A side is single-fp16; B keeps the fp16 hi/lo split -> B rel err ~2^-22.)
// ---------------------------------------------------------------------------
__global__ void wconvert_kernel(const float* __restrict__ weights,
                                const float* __restrict__ roots,
                                unsigned short* __restrict__ wblk) {
    const int total = LAYERS * SEGS * KSTEPS * 256 * 32;
    int idx = blockIdx.x * blockDim.x + threadIdx.x;
    if (idx >= total) return;
    const int kk  = idx & 31;
    const int col = (idx >> 5) & 255;
    const int ks  = (idx >> 13) & 7;
    const int sl  = idx >> 16;            // l*9 + seg
    const int seg = sl % SEGS, l = sl / SEGS;
    const int krow = ks * 32 + kk;
    float v;
    if (seg == 0)
        v = roots[((size_t)l * 256 + krow) * 256 + col];
    else
        v = weights[(((size_t)l * RNUM + (seg - 1)) * 256 + krow) * 256 + col];
    const unsigned short hi = f2h(v);
    const unsigned short lo = f2h(v - h2f(hi));
    const size_t base = ((size_t)sl * KSTEPS + ks) * 16384;
    wblk[base + (size_t)col * 32 + kk] = hi;
    wblk[base + 8192 + (size_t)col * 32 + kk] = lo;
}

// ---------------------------------------------------------------------------
// Fused RGCN layer, round 8: fp16 single-A + fp16 hi/lo B (R7 numerics,
// PASSED at absmax 7.8e-3) with __launch_bounds__(512, 4).
//   R7's (512,8) forced a 64-VGPR budget -> allocator spilled to scratch
//   (VGPR=32, FETCH 1.76 GB, MfmaUtil 3%). 4 waves/EU = 128-VGPR budget
//   fits the ~100-reg live set with zero spills; occupancy 2 blocks/CU
//   (VGPR-bound; LDS 33.8 KB would allow 4).
// ---------------------------------------------------------------------------
template <int ACT>  // 0 = relu, 1 = sigmoid
__global__ __launch_bounds__(512, 4)
void layer_kernel(const float* __restrict__ hin,            // [N, D] fp32
                  const unsigned short* __restrict__ wl,    // this layer's wblk
                  const float* __restrict__ bias,           // [D]
                  const int* __restrict__ pp,               // [N*8+1], key=r*N+d
                  const int* __restrict__ epk,              // [E] packed lr|src
                  float* __restrict__ hout,                 // [N, D]
                  int N) {
    __shared__ unsigned short Ahi[BM * AST];   // 33,792 B

    const int tid = threadIdx.x;
    const int wv = tid >> 6;          // wave 0..7 -> cols [wv*32, wv*32+32)
    const int lane = tid & 63;
    const int lm = lane & 15;         // MFMA row/col lane index
    const int lq = lane >> 4;         // MFMA k-quad
    const int rb = blockIdx.x * BM;
    const int cbase = wv * 32 + lm;

    f32x4 acc[4][2];                  // [row-tile][col-tile]
#pragma unroll
    for (int i = 0; i < 4; ++i)
#pragma unroll
        for (int j = 0; j < 2; ++j) acc[i][j] = (f32x4)0.f;

    // ---- hoist all segment range boundaries: lane l<16 -> (rel=l>>1, fence=l&1)
    int bnd = 0;
    if (lane < 16) {
        const int r = lane >> 1;
        int row = rb + wv * 8 + ((lane & 1) << 3);
        if (row > N) row = N;                   // tail clamp -> empty ranges
        bnd = pp[r * N + row];
    }

    auto flushrow = [&](int row, const float4& s) {
        ushort4 h4;
        h4.x = f2h(s.x); h4.y = f2h(s.y);
        h4.z = f2h(s.z); h4.w = f2h(s.w);
        *reinterpret_cast<ushort4*>(&Ahi[row * AST + lane * 4]) = h4;
    };

    // ---- stage seg 0 (root): dense copy of block rows
    for (int m = wv; m < BM; m += NWAVE) {
        int r = rb + m;
        if (r >= N) r = N - 1;                 // tail clamp; store is masked later
        const float4 v = *reinterpret_cast<const float4*>(hin + (size_t)r * D + lane * 4);
        ushort4 h4;
        h4.x = f2h(v.x); h4.y = f2h(v.y);
        h4.z = f2h(v.z); h4.w = f2h(v.w);
        *reinterpret_cast<ushort4*>(&Ahi[m * AST + lane * 4]) = h4;
    }

    // ---- prefetch edge list for segment 1
    int nbeg = __builtin_amdgcn_readlane(bnd, 0);
    int ncnt = __builtin_amdgcn_readlane(bnd, 1) - nbeg;
    int ep = 0;
    { const int c = ncnt < 64 ? ncnt : 64; if (lane < c) ep = epk[nbeg + lane]; }

    wave_barrier();    // seg-0 tile visible

    for (int seg = 0; seg < SEGS; ++seg) {
        // ============ MFMA phase on staged A tile ============
        const unsigned short* wseg = wl + (size_t)seg * KSTEPS * 16384;
        for (int ks = 0; ks < KSTEPS; ++ks) {
            const unsigned short* wks = wseg + (size_t)ks * 16384;
            // B fragments from global (L2): lane holds B[k = lq*8+j][col]
            f16x8 bh[2], bl[2];
#pragma unroll
            for (int ct = 0; ct < 2; ++ct) {
                const int c = cbase + ct * 16;
                bh[ct] = *reinterpret_cast<const f16x8*>(wks + (size_t)c * 32 + lq * 8);
                bl[ct] = *reinterpret_cast<const f16x8*>(wks + 8192 + (size_t)c * 32 + lq * 8);
            }
            // A fragments: lane holds A[m = rt*16+lm][k = lq*8 + j]
            f16x8 ah[4];
#pragma unroll
            for (int rt = 0; rt < 4; ++rt) {
                const int off = (rt * 16 + lm) * AST + ks * 32 + lq * 8;
                ah[rt] = *reinterpret_cast<const f16x8*>(&Ahi[off]);
            }
#pragma unroll
            for (int rt = 0; rt < 4; ++rt)
#pragma unroll
                for (int ct = 0; ct < 2; ++ct) {
                    acc[rt][ct] = __builtin_amdgcn_mfma_f32_16x16x32_f16(
                        ah[rt], bl[ct], acc[rt][ct], 0, 0, 0);
                    acc[rt][ct] = __builtin_amdgcn_mfma_f32_16x16x32_f16(
                        ah[rt], bh[ct], acc[rt][ct], 0, 0, 0);
                }
        }

        // ============ stage next segment ============
        if (seg + 1 < SEGS) {
            wave_barrier();            // all waves done reading the A tile

            // zero this wave's 8 rows (covers edge-less rows; flushes overwrite)
#pragma unroll
            for (int m = 0; m < 8; ++m) {
                const int row = wv * 8 + m;
                *reinterpret_cast<ushort4*>(&Ahi[row * AST + lane * 4]) =
                    make_ushort4(0, 0, 0, 0);
            }

            // gather: run-accumulate the wave's contiguous edge range
            {
                const int beg = nbeg, cnt = ncnt;
                int e0 = ep;
                int cur = -1;
                float4 sum = make_float4(0.f, 0.f, 0.f, 0.f);
                int processed = 0;
                while (processed < cnt) {
                    int avail = cnt - processed;
                    if (avail > 64) avail = 64;
                    int inner = 0;
                    while (inner < avail) {
                        const int take = (avail - inner) < 8 ? (avail - inner) : 8;
                        int pk[8]; float4 u[8];
#pragma unroll
                        for (int i = 0; i < 8; ++i) {
                            if (i < take) {
                                pk[i] = __builtin_amdgcn_readlane(e0, inner + i);
                                const int s = pk[i] & SMASK;
                                u[i] = *reinterpret_cast<const float4*>(
                                    hin + (size_t)s * D + lane * 4);
                            }
                        }
#pragma unroll
                        for (int i = 0; i < 8; ++i) {
                            if (i < take) {
                                const int lr = (int)(((unsigned)pk[i]) >> 26);
                                if (lr != cur) {
                                    if (cur >= 0) flushrow(cur, sum);
                                    sum = make_float4(0.f, 0.f, 0.f, 0.f);
                                    cur = lr;
                                }
                                sum.x += u[i].x; sum.y += u[i].y;
                                sum.z += u[i].z; sum.w += u[i].w;
                            }
                        }
                        inner += take;
                    }
                    processed += avail;
                    if (processed < cnt) {
                        int c = cnt - processed; if (c > 64) c = 64;
                        e0 = 0;
                        if (lane < c) e0 = epk[beg + processed + lane];
                    }
                }
                if (cur >= 0) flushrow(cur, sum);
            }

            // prefetch edge list for segment seg+2 (hides under next MFMA phase)
            if (seg + 2 < SEGS) {
                nbeg = __builtin_amdgcn_readlane(bnd, (seg + 1) * 2);
                ncnt = __builtin_amdgcn_readlane(bnd, (seg + 1) * 2 + 1) - nbeg;
                ep = 0;
                const int c = ncnt < 64 ? ncnt : 64;
                if (lane < c) ep = epk[nbeg + lane];
            }

            wave_barrier();            // staged A tile visible
        }
    }

    // ---- epilogue: C/D layout col=lane&15, row=(lane>>4)*4+reg
#pragma unroll
    for (int ct = 0; ct < 2; ++ct) {
        const int col = wv * 32 + ct * 16 + lm;
        const float bb = bias[col];
#pragma unroll
        for (int rt = 0; rt < 4; ++rt) {
#pragma unroll
            for (int i = 0; i < 4; ++i) {
                const int row = rb + rt * 16 + lq * 4 + i;
                if (row < N) {
                    float z = acc[rt][ct][i] + bb;
                    z = (ACT == 0) ? fmaxf(z, 0.f) : 1.f / (1.f + __expf(-z));
                    hout[(size_t)row * D + col] = z;
                }
            }
        }
    }
}

// ---------------------------------------------------------------------------
extern "C" void kernel_launch(void* const* d_in, const int* in_sizes, int n_in,
                              void* d_out, int out_size, void* d_ws, size_t ws_size,
                              hipStream_t stream) {
    const float* x       = (const float*)d_in[0];
    const float* weights = (const float*)d_in[1];   // [L, R, D, D]
    const float* roots   = (const float*)d_in[2];   // [L, D, D]
    const float* biases  = (const float*)d_in[3];   // [L, D]
    const void*  ei      = d_in[4];                 // [2, E]
    const void*  et      = d_in[5];                 // [E]

    const int N = in_sizes[0] / D;    // 50000
    const int E = in_sizes[4] / 2;    // 300000
    const int NP = N * RNUM;          // 400000

    char* ws = (char*)d_ws;
    int* flag = (int*)ws;
    int* pp   = (int*)(ws + 256);     // NP+1
    int* cur  = pp + (NP + 1);        // NP
    int* bsum = cur + NP;             // 512
    int* epk  = bsum + 512;           // E (packed lr|src)
    size_t hoff = (256 + (size_t)(NP + 1 + NP + 512 + E) * 4 + 255) & ~(size_t)255;
    float* h1 = (float*)(ws + hoff);
    unsigned short* wblk = (unsigned short*)(ws + hoff + (size_t)N * D * sizeof(float));

    // --- W conversion to MFMA-blocked fp16 hi/lo (all 3 layers) ---
    const int wtotal = LAYERS * SEGS * KSTEPS * 256 * 32;
    wconvert_kernel<<<(wtotal + 255) / 256, 256, 0, stream>>>(weights, roots, wblk);

    // --- build (rel,dst)-sorted CSR ---
    detect_kernel<<<1, 256, 0, stream>>>((const int*)ei, flag);
    const int zn = 2 * NP + 513;
    zero_kernel<<<(zn + 255) / 256, 256, 0, stream>>>(pp, zn);
    const int eb = (E + 255) / 256;
    count_kernel<<<eb, 256, 0, stream>>>(ei, et, flag, pp, E, N);
    const int nb = (NP + 1023) / 1024;
    scan_blocks_kernel<<<nb, 1024, 0, stream>>>(pp, bsum, NP);
    scan_sums_kernel<<<1, 512, 0, stream>>>(bsum, nb);
    scan_add_kernel<<<nb, 1024, 0, stream>>>(pp, bsum, NP, E);
    fill_kernel<<<eb, 256, 0, stream>>>(ei, et, flag, pp, cur, epk, E, N);

    // --- 3 fused layers ---
    const int tiles = (N + BM - 1) / BM;   // 782
    const size_t wlayer = (size_t)SEGS * KSTEPS * 16384;
    const float* hin = x;
    for (int l = 0; l < LAYERS; ++l) {
        float* hout = (l == 1) ? h1 : (float*)d_out;   // l0->d_out, l1->h1, l2->d_out
        const unsigned short* wlp = wblk + (size_t)l * wlayer;
        const float* bl = biases + (size_t)l * D;
        if (l == LAYERS - 1)
            layer_kernel<1><<<tiles, 512, 0, stream>>>(hin, wlp, bl, pp, epk, hout, N);
        else
            layer_kernel<0><<<tiles, 512, 0, stream>>>(hin, wlp, bl, pp, epk, hout, N);
        hin = hout;
    }
}